// Round 1
// baseline (2152.284 us; speedup 1.0000x reference)
//
#include <hip/hip_runtime.h>

#define HH 32
#define WW 32
#define CC 256
#define OO 512
#define BB 64
#define OT 32            // o-tile per block -> 16 tiles
#define HWC (HH*WW*CC)   // batch stride in x
#define HWO (HH*WW*OO)   // batch stride in out
#define EPS 1e-3f
#define ALPHA 0.2f

__global__ __launch_bounds__(256) void cdot_fused(
    const float* __restrict__ xr, const float* __restrict__ xi,
    const float* __restrict__ w,
    const float* __restrict__ gr, const float* __restrict__ br,
    const float* __restrict__ mr, const float* __restrict__ vr,
    const float* __restrict__ gi, const float* __restrict__ bi,
    const float* __restrict__ mi, const float* __restrict__ vi,
    float* __restrict__ outr, float* __restrict__ outi)
{
    __shared__ float s_wr[CC][OT];   // 32 KB
    __shared__ float s_wi[CC][OT];   // 32 KB

    const int blk = blockIdx.x;
    const int uv  = blk >> 4;            // 0..1023
    const int ot  = blk & 15;            // 0..15
    const int u = uv >> 5, v = uv & 31;
    const int o0 = ot * OT;
    const int tid = threadIdx.x;
    const int j = tid & 31;              // o within tile

    // 9 twiddle factors for this (u,v): e^{-2pi i (u p + v q)/32}
    float cs[9], sn[9];
    #pragma unroll
    for (int p = 0; p < 3; ++p) {
        #pragma unroll
        for (int q = 0; q < 3; ++q) {
            int k = (u*p + v*q) & 31;
            float a = (float)k * 0.0625f;      // angle / pi = 2k/32
            cs[p*3+q] = cospif(a);
            sn[p*3+q] = sinpif(a);
        }
    }

    // ---- Phase 1: build freq-domain weight tile into LDS ----
    // w layout: (3,3,C,O) -> w[((p*3+q)*CC + c)*OO + o]
    for (int c = (tid >> 5); c < CC; c += 8) {
        float ar = 0.f, ai = 0.f;
        #pragma unroll
        for (int t = 0; t < 9; ++t) {
            float wv = w[(size_t)(t*CC + c)*OO + o0 + j];
            ar = fmaf(cs[t], wv, ar);
            ai = fmaf(-sn[t], wv, ai);   // imag = -sum sin * w
        }
        s_wr[c][j] = ar;
        s_wi[c][j] = ai;
    }
    __syncthreads();

    // ---- Phase 2: 64b x 32o x 256c complex contraction ----
    const int g = tid >> 5;              // batch group 0..7
    const int b0 = g * 8;                // 8 batches per thread
    const int uvoff = (u*WW + v)*CC;
    const float* xr0 = xr + uvoff;
    const float* xi0 = xi + uvoff;

    float accR[8], accI[8];
    #pragma unroll
    for (int bb = 0; bb < 8; ++bb) { accR[bb] = 0.f; accI[bb] = 0.f; }

    for (int c = 0; c < CC; c += 4) {
        const float wr0 = s_wr[c+0][j], wi0 = s_wi[c+0][j];
        const float wr1 = s_wr[c+1][j], wi1 = s_wi[c+1][j];
        const float wr2 = s_wr[c+2][j], wi2 = s_wi[c+2][j];
        const float wr3 = s_wr[c+3][j], wi3 = s_wi[c+3][j];
        #pragma unroll
        for (int bb = 0; bb < 8; ++bb) {
            const float4 a = *(const float4*)(xr0 + (size_t)(b0+bb)*HWC + c);
            const float4 d = *(const float4*)(xi0 + (size_t)(b0+bb)*HWC + c);
            accR[bb] += a.x*wr0 + a.y*wr1 + a.z*wr2 + a.w*wr3
                      + d.x*wi0 + d.y*wi1 + d.z*wi2 + d.w*wi3;
            accI[bb] += a.x*wi0 + a.y*wi1 + a.z*wi2 + a.w*wi3
                      - d.x*wr0 - d.y*wr1 - d.z*wr2 - d.w*wr3;
        }
    }

    // ---- Epilogue: BN (inference) + LeakyReLU, coalesced stores ----
    const int o = o0 + j;
    const float scR = gr[o] * rsqrtf(vr[o] + EPS);
    const float mR  = mr[o], bR = br[o];
    const float scI = gi[o] * rsqrtf(vi[o] + EPS);
    const float mI  = mi[o], bI = bi[o];
    const size_t obase = (size_t)(u*WW + v)*OO + o0 + j;

    #pragma unroll
    for (int bb = 0; bb < 8; ++bb) {
        const size_t idx = obase + (size_t)(b0+bb)*HWO;
        float yr = (accR[bb] - mR)*scR + bR;
        outr[idx] = (yr >= 0.f) ? yr : ALPHA*yr;
        float yi = (accI[bb] - mI)*scI + bI;
        outi[idx] = (yi >= 0.f) ? yi : ALPHA*yi;
    }
}

extern "C" void kernel_launch(void* const* d_in, const int* in_sizes, int n_in,
                              void* d_out, int out_size, void* d_ws, size_t ws_size,
                              hipStream_t stream) {
    const float* xr = (const float*)d_in[0];
    const float* xi = (const float*)d_in[1];
    const float* w  = (const float*)d_in[2];
    const float* gr = (const float*)d_in[3];
    const float* br = (const float*)d_in[4];
    const float* mr = (const float*)d_in[5];
    const float* vr = (const float*)d_in[6];
    const float* gi = (const float*)d_in[7];
    const float* bi = (const float*)d_in[8];
    const float* mi = (const float*)d_in[9];
    const float* vi = (const float*)d_in[10];

    float* outr = (float*)d_out;
    float* outi = outr + (size_t)BB*HH*WW*OO;

    dim3 grid(1024 * (OO/OT));   // (u,v) x o-tiles = 16384 blocks
    dim3 block(256);
    cdot_fused<<<grid, block, 0, stream>>>(xr, xi, w,
                                           gr, br, mr, vr,
                                           gi, bi, mi, vi,
                                           outr, outi);
}

// Round 3
// 400.880 us; speedup vs baseline: 5.3689x; 5.3689x over previous
//
#include <hip/hip_runtime.h>
#include <hip/hip_bf16.h>

#define HH 32
#define WW 32
#define CC 256
#define OO 512
#define BB 64
#define HWC (HH*WW*CC)
#define HWO (HH*WW*OO)
#define EPS 1e-3f
#define ALPHA 0.2f

typedef __attribute__((ext_vector_type(8))) short short8;
typedef __attribute__((ext_vector_type(4))) float f32x4;
typedef __attribute__((ext_vector_type(4))) int int4_;

__device__ __forceinline__ short f2bf(float f) {
    return (short)__builtin_bit_cast(unsigned short, __float2bfloat16(f));
}
__device__ __forceinline__ float bf2f(short s) {
    return __uint_as_float(((unsigned)(unsigned short)s) << 16);
}

// ---- kernel 0: transpose taps (3,3,C,O) f32 -> (t,O,C) bf16 in ws ----
// 64x64 tiles through LDS, coalesced both sides, +1-pad banks.
__global__ __launch_bounds__(256) void transpose_taps(const float* __restrict__ w,
                                                      short* __restrict__ tt) {
    __shared__ float tile[64][65];
    const int bid = blockIdx.x;
    const int t  = bid >> 5;          // 0..8
    const int ct = (bid >> 3) & 3;    // c tile
    const int ob = bid & 7;           // o tile
    const int c0 = ct * 64, o0 = ob * 64;
    const int tid = threadIdx.x;
    const int col = tid & 63;
    const int rq  = tid >> 6;         // 0..3
    #pragma unroll
    for (int r = 0; r < 16; ++r) {
        int c_loc = r * 4 + rq;
        tile[c_loc][col] = w[(size_t)(t * CC + c0 + c_loc) * OO + o0 + col];
    }
    __syncthreads();
    #pragma unroll
    for (int r = 0; r < 16; ++r) {
        int o_loc = r * 4 + rq;
        tt[(size_t)(t * OO + o0 + o_loc) * CC + c0 + col] = f2bf(tile[col][o_loc]);
    }
}

// ---- main fused kernel ----
__global__ __launch_bounds__(256, 2) void cdot_mfma(
    const float* __restrict__ xr, const float* __restrict__ xi,
    const short* __restrict__ taps,     // (t, o, c) bf16
    const float* __restrict__ gr, const float* __restrict__ br,
    const float* __restrict__ mr, const float* __restrict__ vr,
    const float* __restrict__ gi, const float* __restrict__ bi,
    const float* __restrict__ mi_, const float* __restrict__ vi,
    float* __restrict__ outr, float* __restrict__ outi)
{
    // sx: [2][64 b][64 c] bf16, XOR-swizzled in 8-elt groups. 16 KB.
    __shared__ short sx[8192];

    const int tid  = threadIdx.x;
    const int lane = tid & 63;
    const int wave = tid >> 6;
    const int laneO = lane & 15;
    const int laneW = lane >> 4;

    const int blk = blockIdx.x;
    const int uv  = blk >> 2;          // 0..1023
    const int ot  = blk & 3;           // o-tile of 128
    const int u = uv >> 5, v = uv & 31;
    const int o0 = ot * 128;
    const int owave = o0 + wave * 32;

    // twiddles e^{-2pi i (u p + v q)/32}  (verified round 1)
    float cs[9], sn[9];
    #pragma unroll
    for (int p = 0; p < 3; ++p) {
        #pragma unroll
        for (int q = 0; q < 3; ++q) {
            int k = (u*p + v*q) & 31;
            float a = (float)k * 0.0625f;
            cs[p*3+q] = cospif(a);
            sn[p*3+q] = sinpif(a);
        }
    }

    f32x4 accR[4][2], accI[4][2];
    #pragma unroll
    for (int m = 0; m < 4; ++m)
        #pragma unroll
        for (int n = 0; n < 2; ++n) { accR[m][n] = (f32x4)(0.0f); accI[m][n] = (f32x4)(0.0f); }

    for (int ch = 0; ch < 4; ++ch) {
        const int kc0 = ch * 64;
        __syncthreads();               // previous sweep's reads done; sx reusable

        // ---- stage x chunk: [2][64 b][64 c] bf16, swizzled (verified r1/r2 pattern) ----
        #pragma unroll
        for (int it = 0; it < 4; ++it) {
            int s  = tid + it * 256;           // 0..1023
            int ri = s >> 9;
            int rr = s & 511;
            int b  = rr >> 3;
            int c8 = (rr & 7) * 8;
            const float* src = (ri ? xi : xr) + (size_t)b * HWC + uv * CC + kc0 + c8;
            float4 f0 = *(const float4*)src;
            float4 f1 = *(const float4*)(src + 4);
            short8 p;
            p[0]=f2bf(f0.x); p[1]=f2bf(f0.y); p[2]=f2bf(f0.z); p[3]=f2bf(f0.w);
            p[4]=f2bf(f1.x); p[5]=f2bf(f1.y); p[6]=f2bf(f1.z); p[7]=f2bf(f1.w);
            int idx = ri * 4096 + b * 64 + (c8 ^ ((b & 7) * 8));
            *(short8*)(sx + idx) = p;
        }
        __syncthreads();

        #pragma unroll
        for (int ks = 0; ks < 2; ++ks) {
            // ---- A fragments from swizzled x LDS ----
            short8 a[4][2];
            #pragma unroll
            for (int m = 0; m < 4; ++m) {
                int b = m * 16 + laneO;
                int cidx = (ks * 32 + laneW * 8) ^ ((b & 7) * 8);
                #pragma unroll
                for (int ri = 0; ri < 2; ++ri)
                    a[m][ri] = *(const short8*)(sx + ri * 4096 + b * 64 + cidx);
            }

            // ---- B fragments constructed directly in registers ----
            // lane needs w_freq[c = cb + e][o = owave + n*16 + laneO], e=0..7
            const int cb = kc0 + ks * 32 + laneW * 8;
            short8 bR[2], bI[2];
            #pragma unroll
            for (int n = 0; n < 2; ++n) {
                int o = owave + n * 16 + laneO;
                const short* tb = taps + (size_t)o * CC + cb;
                float ar[8], ai[8];
                #pragma unroll
                for (int e = 0; e < 8; ++e) { ar[e] = 0.f; ai[e] = 0.f; }
                #pragma unroll
                for (int t = 0; t < 9; ++t) {
                    short8 tp = *(const short8*)(tb + (size_t)t * (OO * CC));
                    #pragma unroll
                    for (int e = 0; e < 8; ++e) {
                        float f = bf2f(tp[e]);
                        ar[e] = fmaf(cs[t], f, ar[e]);
                        ai[e] = fmaf(-sn[t], f, ai[e]);
                    }
                }
                #pragma unroll
                for (int e = 0; e < 8; ++e) { bR[n][e] = f2bf(ar[e]); bI[n][e] = f2bf(ai[e]); }
            }

            // negated xi fragments for the imaginary part
            short8 an[4];
            #pragma unroll
            for (int m = 0; m < 4; ++m) {
                int4_ tneg = __builtin_bit_cast(int4_, a[m][1]);
                tneg ^= (int)0x80008000u;
                an[m] = __builtin_bit_cast(short8, tneg);
            }

            #pragma unroll
            for (int m = 0; m < 4; ++m) {
                #pragma unroll
                for (int n = 0; n < 2; ++n) {
                    accR[m][n] = __builtin_amdgcn_mfma_f32_16x16x32_bf16(a[m][0], bR[n], accR[m][n], 0, 0, 0);
                    accR[m][n] = __builtin_amdgcn_mfma_f32_16x16x32_bf16(a[m][1], bI[n], accR[m][n], 0, 0, 0);
                    accI[m][n] = __builtin_amdgcn_mfma_f32_16x16x32_bf16(a[m][0], bI[n], accI[m][n], 0, 0, 0);
                    accI[m][n] = __builtin_amdgcn_mfma_f32_16x16x32_bf16(an[m],   bR[n], accI[m][n], 0, 0, 0);
                }
            }
        }
    }

    // ---- epilogue: BN + LeakyReLU, coalesced stores (verified round 1 math) ----
    #pragma unroll
    for (int n = 0; n < 2; ++n) {
        int o = owave + n * 16 + laneO;
        float scR = gr[o] * rsqrtf(vr[o] + EPS);
        float mR = mr[o], bR_ = br[o];
        float scI = gi[o] * rsqrtf(vi[o] + EPS);
        float mI = mi_[o], bI_ = bi[o];
        #pragma unroll
        for (int m = 0; m < 4; ++m) {
            #pragma unroll
            for (int e = 0; e < 4; ++e) {
                int b = m * 16 + laneW * 4 + e;
                size_t idx = (size_t)b * HWO + (size_t)uv * OO + o;
                float yr = (accR[m][n][e] - mR) * scR + bR_;
                outr[idx] = (yr >= 0.f) ? yr : ALPHA * yr;
                float yi = (accI[m][n][e] - mI) * scI + bI_;
                outi[idx] = (yi >= 0.f) ? yi : ALPHA * yi;
            }
        }
    }
}

extern "C" void kernel_launch(void* const* d_in, const int* in_sizes, int n_in,
                              void* d_out, int out_size, void* d_ws, size_t ws_size,
                              hipStream_t stream) {
    const float* xr = (const float*)d_in[0];
    const float* xi = (const float*)d_in[1];
    const float* w  = (const float*)d_in[2];
    const float* gr = (const float*)d_in[3];
    const float* br = (const float*)d_in[4];
    const float* mr = (const float*)d_in[5];
    const float* vr = (const float*)d_in[6];
    const float* gi = (const float*)d_in[7];
    const float* bi = (const float*)d_in[8];
    const float* mi_ = (const float*)d_in[9];
    const float* vi = (const float*)d_in[10];

    short* taps_t = (short*)d_ws;               // 9*512*256 bf16 = 2.36 MB
    float* outr = (float*)d_out;
    float* outi = outr + (size_t)BB * HWO;

    transpose_taps<<<288, 256, 0, stream>>>(w, taps_t);
    cdot_mfma<<<4096, 256, 0, stream>>>(xr, xi, taps_t,
                                        gr, br, mr, vr,
                                        gi, bi, mi_, vi,
                                        outr, outi);
}